// Round 6
// baseline (7383.816 us; speedup 1.0000x reference)
//
#include <hip/hip_runtime.h>
#include <hip/hip_cooperative_groups.h>

namespace cg = cooperative_groups;

#define N_      800
#define C_      64
#define TRS_    40
#define SPT_    10
#define BUF_    120
#define T_      400
#define STRIDE  528           // per-row history stride in words (520 used)
#define KPL     13            // edges per lane: 13*64 = 832 >= 800
#define SENT    0x7FC00BADu   // qNaN sentinel for "not yet written"
#define NEAR_D  4             // d < 4  : per-step scattered ALD poll
#define MID_D   16            // 4<=d<16: 4-step float4 windows; d>=16: 16-step windows

#define A_F     (-0.5f)
#define OMEGA_F (10.0f)
#define G_F     (500.0f)
#define KGI_F   (5.0f)
#define DT_F    (1e-4f)

#define ALD(p)    __hip_atomic_load((p), __ATOMIC_RELAXED, __HIP_MEMORY_SCOPE_AGENT)
#define AST(p,v)  __hip_atomic_store((p), (v), __ATOMIC_RELAXED, __HIP_MEMORY_SCOPE_AGENT)

// ---------------- prelude kernels (unchanged from champion R0) ----------------

__global__ void k_sumsq(const float* __restrict__ sc, float* __restrict__ sumsq) {
    __shared__ float sh[4];
    int tid = threadIdx.x;
    int idx = blockIdx.x * 256 + tid;
    float s = 0.f;
    for (int i = idx; i < N_ * N_; i += 256 * 256) { float v = sc[i]; s += v * v; }
    #pragma unroll
    for (int o = 1; o < 64; o <<= 1) s += __shfl_xor(s, o, 64);
    if ((tid & 63) == 0) sh[tid >> 6] = s;
    __syncthreads();
    if (tid == 0) atomicAdd(sumsq, sh[0] + sh[1] + sh[2] + sh[3]);
}

__global__ void k_detect(const int* __restrict__ dw, int* __restrict__ flag) {
    __shared__ int sh[4];
    int tid = threadIdx.x;
    int v = 0;
    for (int idx = 2 * tid + 1; idx < 800; idx += 512) v |= dw[idx];
    #pragma unroll
    for (int o = 1; o < 64; o <<= 1) v |= __shfl_xor(v, o, 64);
    if ((tid & 63) == 0) sh[tid >> 6] = v;
    __syncthreads();
    if (tid == 0) flag[0] = ((sh[0] | sh[1] | sh[2] | sh[3]) == 0) ? 1 : 0; // 1 => int64
}

// per-row history: row j, time tau at word j*STRIDE + 120 + tau (tau in [-120,399])
__global__ void k_init(const float* __restrict__ hE, unsigned int* __restrict__ xh) {
    int idx = blockIdx.x * 256 + threadIdx.x;
    if (idx >= N_ * 520) return;
    int j = idx / 520, s = idx - j * 520;
    unsigned int v = (s < 120) ? __float_as_uint(hE[j * BUF_ + (119 - s)]) : SENT;
    xh[j * STRIDE + s] = v;
}

// ---------------- main persistent kernel ----------------
// Champion R0 structure (elastic, no barriers, register fps) with the scattered
// per-step poll class cut 4x (d<4 only) and a new mid class d in [4,16) served
// by the proven float4-window idiom at 4-step cadence. Far batches (d>=16) are
// phase-staggered per row (p = i&15) to smooth chip-wide request bursts.

__global__ void __launch_bounds__(512, 1) k_main(
    const float* __restrict__ sc, const int* __restrict__ dw,
    const float* __restrict__ hx, const float* __restrict__ external,
    const float* __restrict__ noise, const float* __restrict__ lm,
    const float* __restrict__ sumsq, const int* __restrict__ flag,
    unsigned int* __restrict__ xh, float* __restrict__ xtr, float* __restrict__ out)
{
    cg::grid_group grid = cg::this_grid();
    const int lane = threadIdx.x & 63;
    const int i = (int)((blockIdx.x * 512 + threadIdx.x) >> 6); // row 0..799

    const float inv_norm = 1.0f / sqrtf(*sumsq);
    const int is64 = *flag;

    // per-lane edge metadata: j = k*64+lane; aw + t = word addr of x_j(t-1-d)
    float wn[KPL], wm[KPL], wf[KPL]; int aw[KPL];
    float rsum = 0.f;
    #pragma unroll
    for (int k = 0; k < KPL; ++k) {
        int j = k * 64 + lane;
        bool valid = (j < N_);
        int jj = valid ? j : 0;
        int base = i * N_ + jj;
        float wv = valid ? fabsf(sc[base]) * inv_norm : 0.f;
        int dv = valid ? dw[is64 ? (base << 1) : base] : 119;
        rsum += wv;
        wn[k] = (valid && dv < NEAR_D) ? wv : 0.f;
        wm[k] = (valid && dv >= NEAR_D && dv < MID_D) ? wv : 0.f;
        wf[k] = (valid && dv >= MID_D) ? wv : 0.f;
        aw[k] = jj * STRIDE + 119 - dv;
    }
    #pragma unroll
    for (int o = 1; o < 64; o <<= 1) rsum += __shfl_xor(rsum, o, 64);

    float x = hx[2 * i], y = hx[2 * i + 1];
    const int p = i & 15;                     // per-row far/mid phase stagger

    #pragma unroll 1
    for (int m = -1; m < 25; ++m) {
        const int tb = p + 16 * m;            // macro-block covers steps [tb, tb+16)
        const int flo = (tb < 0) ? -tb : 0;
        const int fhi = (400 - tb < 16) ? (400 - tb) : 16;

        // ---- far windows (d>=16): one 20-word window per edge per macro-block ----
        float fps[16];
        #pragma unroll
        for (int s = 0; s < 16; ++s) fps[s] = 0.f;

        if (flo < fhi) {
            #pragma unroll
            for (int k = 0; k < KPL; ++k) {
                bool fm = (wf[k] != 0.f);
                int a = aw[k] + tb;           // word addr at s=0 (may sit in row pad)
                int pp = a & 3;
                int A = a - pp;               // 16B-aligned
                float4 q0, q1, q2, q3, q4;
                if (fm) {
                    const float4* f4 = reinterpret_cast<const float4*>((const float*)xh + A);
                    q0 = f4[0]; q1 = f4[1]; q2 = f4[2]; q3 = f4[3]; q4 = f4[4];
                } else {
                    q0 = q1 = q2 = q3 = q4 = make_float4(0.f, 0.f, 0.f, 0.f);
                }
                float win[20] = { q0.x,q0.y,q0.z,q0.w, q1.x,q1.y,q1.z,q1.w,
                                  q2.x,q2.y,q2.z,q2.w, q3.x,q3.y,q3.z,q3.w,
                                  q4.x,q4.y,q4.z,q4.w };
                const int zlo = pp + flo, zhi = pp + fhi;
                int g = 0;
                while (true) {                // stale-SENT -> ALD retry (proven idiom)
                    int pend = 0;
                    #pragma unroll
                    for (int z = 0; z < 20; ++z)
                        pend |= (int)((z >= zlo) & (z < zhi) &
                                      (__float_as_uint(win[z]) == SENT));
                    if (!__any(pend)) break;
                    if (++g > 1000000) break; // safety valve
                    #pragma unroll
                    for (int z = 0; z < 20; ++z)
                        if ((z >= zlo) && (z < zhi) && __float_as_uint(win[z]) == SENT)
                            win[z] = __uint_as_float(ALD(&xh[A + z]));
                }
                float wk = wf[k];
                #pragma unroll
                for (int s = 0; s < 16; ++s) {
                    if ((s >= flo) & (s < fhi)) {       // value = win[pp+s], 3 cndmask
                        float v01 = (pp & 1) ? win[s + 1] : win[s];
                        float v23 = (pp & 1) ? win[s + 3] : win[s + 2];
                        float v   = (pp & 2) ? v23 : v01;
                        fps[s] += wk * v;
                    }
                }
            }
        }

        float fm4[4] = {0.f, 0.f, 0.f, 0.f};

        #pragma unroll
        for (int s = 0; s < 16; ++s) {
            const int t = tb + s;

            // ---- mid windows (4<=d<16): refill fm4 each quad (compile-time slot) ----
            if ((s & 3) == 0) {
                if (t + 3 >= 0 && t < 400) {
                    const int mlo = (t < 0) ? -t : 0;
                    const int mhi = (400 - t < 4) ? (400 - t) : 4;
                    #pragma unroll
                    for (int r = 0; r < 4; ++r) fm4[r] = 0.f;
                    #pragma unroll
                    for (int k = 0; k < KPL; ++k) {
                        bool mm = (wm[k] != 0.f);
                        int a = aw[k] + t;
                        int pp = a & 3;
                        int A = a - pp;
                        float4 q0, q1;
                        if (mm) {
                            const float4* f4 = reinterpret_cast<const float4*>((const float*)xh + A);
                            q0 = f4[0]; q1 = f4[1];
                        } else {
                            q0 = q1 = make_float4(0.f, 0.f, 0.f, 0.f);
                        }
                        float win[8] = { q0.x,q0.y,q0.z,q0.w, q1.x,q1.y,q1.z,q1.w };
                        const int zlo = pp + mlo, zhi = pp + mhi;
                        int g = 0;
                        while (true) {
                            int pend = 0;
                            #pragma unroll
                            for (int z = 0; z < 8; ++z)
                                pend |= (int)((z >= zlo) & (z < zhi) &
                                              (__float_as_uint(win[z]) == SENT));
                            if (!__any(pend)) break;
                            if (++g > 1000000) break;   // safety valve
                            #pragma unroll
                            for (int z = 0; z < 8; ++z)
                                if ((z >= zlo) && (z < zhi) && __float_as_uint(win[z]) == SENT)
                                    win[z] = __uint_as_float(ALD(&xh[A + z]));
                        }
                        float wk = wm[k];
                        #pragma unroll
                        for (int r = 0; r < 4; ++r) {
                            if ((r >= mlo) & (r < mhi)) {
                                float v01 = (pp & 1) ? win[r + 1] : win[r];
                                float v23 = (pp & 1) ? win[r + 3] : win[r + 2];
                                float v   = (pp & 2) ? v23 : v01;
                                fm4[r] += wk * v;
                            }
                        }
                    }
                }
            }

            if (t >= 0 && t < 400) {
                // ---- near poll (d<4): ~27 cells, proven elastic pattern ----
                unsigned int vv[KPL];
                #pragma unroll
                for (int k = 0; k < KPL; ++k)
                    vv[k] = (wn[k] != 0.f) ? ALD(&xh[aw[k] + t]) : 0u;
                int g = 0;
                while (true) {
                    int pend = 0;
                    #pragma unroll
                    for (int k = 0; k < KPL; ++k) pend |= (vv[k] == SENT) ? 1 : 0;
                    if (!__any(pend)) break;
                    if (++g > 1000000) break;           // safety valve
                    #pragma unroll
                    for (int k = 0; k < KPL; ++k)
                        if (vv[k] == SENT) vv[k] = ALD(&xh[aw[k] + t]);
                }
                float acc = fps[s] + fm4[s & 3];
                #pragma unroll
                for (int k = 0; k < KPL; ++k) acc += wn[k] * __uint_as_float(vv[k]);
                #pragma unroll
                for (int o = 1; o < 64; o <<= 1) acc += __shfl_xor(acc, o, 64);

                // ---- integrate / publish ----
                int tr = (t * 205) >> 11;               // t/10 for t<400
                int sp = t - tr * 10;
                float u  = external[(i * SPT_ + sp) * TRS_ + tr];
                float n0 = noise[(t * N_ + i) * 2 + 0];
                float n1 = noise[(t * N_ + i) * 2 + 1];

                float r2 = x * x + y * y;
                float dx = (A_F - r2) * x - OMEGA_F * y + G_F * (acc - rsum * x) + KGI_F * u;
                float dy = (A_F - r2) * y + OMEGA_F * x;
                x = x + DT_F * dx + n0;
                y = y + DT_F * dy + n1;

                if (lane == 0) {
                    AST(&xh[i * STRIDE + 120 + t], __float_as_uint(x));
                    if (sp == SPT_ - 1) xtr[tr * N_ + i] = x;
                }
            }
        }
    }

    grid.sync();   // make xtr visible for the epilogue

    // epilogue: out[c*TRS + tr] = 5 * dot(xtr[tr,:], lm[c,:]) - 2
    for (int o = i; o < C_ * TRS_; o += 800) {
        int c = o / TRS_, tr = o - c * TRS_;
        float s = 0.f;
        #pragma unroll
        for (int k = 0; k < KPL; ++k) {
            int n = k * 64 + lane;
            if (n < N_) s += xtr[tr * N_ + n] * lm[c * N_ + n];
        }
        #pragma unroll
        for (int o2 = 1; o2 < 64; o2 <<= 1) s += __shfl_xor(s, o2, 64);
        if (lane == 0) out[o] = 5.0f * s - 2.0f;
    }
}

// ---------------- launch (identical shape to champion R0) ----------------

extern "C" void kernel_launch(void* const* d_in, const int* in_sizes, int n_in,
                              void* d_out, int out_size, void* d_ws, size_t ws_size,
                              hipStream_t stream) {
    const float* external = (const float*)d_in[0];
    const float* hx       = (const float*)d_in[1];
    const float* hE       = (const float*)d_in[2];
    const float* sc       = (const float*)d_in[3];
    const float* lm       = (const float*)d_in[4];
    const float* noise    = (const float*)d_in[5];
    const int*   delays   = (const int*)  d_in[6];
    float* out = (float*)d_out;

    float*        sumsq = (float*)d_ws;                    // ws[0]
    int*          flag  = (int*)d_ws + 1;                  // ws[1]
    unsigned int* xh    = (unsigned int*)d_ws + 64;        // 800*528 words
    float*        xtr   = (float*)(xh + N_ * STRIDE);      // 40*800 floats

    hipMemsetAsync(d_ws, 0, 8, stream);
    k_sumsq<<<256, 256, 0, stream>>>(sc, sumsq);
    k_detect<<<1, 256, 0, stream>>>(delays, flag);
    k_init<<<(N_ * 520 + 255) / 256, 256, 0, stream>>>(hE, xh);

    void* args[] = { (void*)&sc, (void*)&delays, (void*)&hx, (void*)&external,
                     (void*)&noise, (void*)&lm, (void*)&sumsq, (void*)&flag,
                     (void*)&xh, (void*)&xtr, (void*)&out };
    hipLaunchCooperativeKernel((const void*)k_main, dim3(100), dim3(512), args, 0, stream);
}

// Round 7
// 5549.600 us; speedup vs baseline: 1.3305x; 1.3305x over previous
//
#include <hip/hip_runtime.h>
#include <hip/hip_cooperative_groups.h>

namespace cg = cooperative_groups;

#define N_      800
#define C_      64
#define TRS_    40
#define SPT_    10
#define BUF_    120
#define T_      400
#define STRIDE  528           // per-row history stride in words (520 used)
#define KPL     13            // edges per lane: 13*64 = 832 >= 800
#define SENT    0x7FC00BADu   // qNaN sentinel for "not yet written"
#define NEAR_D  4             // d < 4  : per-step scattered ALD poll
#define MID_D   16            // 4<=d<16: 4-step float4 windows; d>=16: 16-step windows

#define A_F     (-0.5f)
#define OMEGA_F (10.0f)
#define G_F     (500.0f)
#define KGI_F   (5.0f)
#define DT_F    (1e-4f)

#define ALD(p)    __hip_atomic_load((p), __ATOMIC_RELAXED, __HIP_MEMORY_SCOPE_AGENT)
#define AST(p,v)  __hip_atomic_store((p), (v), __ATOMIC_RELAXED, __HIP_MEMORY_SCOPE_AGENT)

// ---------------- prelude kernels (unchanged from champion R0) ----------------

__global__ void k_sumsq(const float* __restrict__ sc, float* __restrict__ sumsq) {
    __shared__ float sh[4];
    int tid = threadIdx.x;
    int idx = blockIdx.x * 256 + tid;
    float s = 0.f;
    for (int i = idx; i < N_ * N_; i += 256 * 256) { float v = sc[i]; s += v * v; }
    #pragma unroll
    for (int o = 1; o < 64; o <<= 1) s += __shfl_xor(s, o, 64);
    if ((tid & 63) == 0) sh[tid >> 6] = s;
    __syncthreads();
    if (tid == 0) atomicAdd(sumsq, sh[0] + sh[1] + sh[2] + sh[3]);
}

__global__ void k_detect(const int* __restrict__ dw, int* __restrict__ flag) {
    __shared__ int sh[4];
    int tid = threadIdx.x;
    int v = 0;
    for (int idx = 2 * tid + 1; idx < 800; idx += 512) v |= dw[idx];
    #pragma unroll
    for (int o = 1; o < 64; o <<= 1) v |= __shfl_xor(v, o, 64);
    if ((tid & 63) == 0) sh[tid >> 6] = v;
    __syncthreads();
    if (tid == 0) flag[0] = ((sh[0] | sh[1] | sh[2] | sh[3]) == 0) ? 1 : 0; // 1 => int64
}

// per-row history: row j, time tau at word j*STRIDE + 120 + tau (tau in [-120,399])
__global__ void k_init(const float* __restrict__ hE, unsigned int* __restrict__ xh) {
    int idx = blockIdx.x * 256 + threadIdx.x;
    if (idx >= N_ * 520) return;
    int j = idx / 520, s = idx - j * 520;
    unsigned int v = (s < 120) ? __float_as_uint(hE[j * BUF_ + (119 - s)]) : SENT;
    xh[j * STRIDE + s] = v;
}

// ---------------- main persistent kernel ----------------
// R6 with the per-row phase stagger REMOVED (single-variable A/B):
// all rows share macro-block grid tb = 16m and quad grid t = 4q, so every
// window-wait is chip-synchronized (rendezvous amortized, like champion R0).
//   d < 4  : per-step scattered ALD poll (~27 cells)
//   4<=d<16: synchronized 4-step float4 quad-windows (2-step slack)
//   d >= 16: synchronized 16-step float4 windows (1-step slack, R0-proven)

__global__ void __launch_bounds__(512, 1) k_main(
    const float* __restrict__ sc, const int* __restrict__ dw,
    const float* __restrict__ hx, const float* __restrict__ external,
    const float* __restrict__ noise, const float* __restrict__ lm,
    const float* __restrict__ sumsq, const int* __restrict__ flag,
    unsigned int* __restrict__ xh, float* __restrict__ xtr, float* __restrict__ out)
{
    cg::grid_group grid = cg::this_grid();
    const int lane = threadIdx.x & 63;
    const int i = (int)((blockIdx.x * 512 + threadIdx.x) >> 6); // row 0..799

    const float inv_norm = 1.0f / sqrtf(*sumsq);
    const int is64 = *flag;

    // per-lane edge metadata: j = k*64+lane; aw + t = word addr of x_j(t-1-d)
    float wn[KPL], wm[KPL], wf[KPL]; int aw[KPL];
    float rsum = 0.f;
    #pragma unroll
    for (int k = 0; k < KPL; ++k) {
        int j = k * 64 + lane;
        bool valid = (j < N_);
        int jj = valid ? j : 0;
        int base = i * N_ + jj;
        float wv = valid ? fabsf(sc[base]) * inv_norm : 0.f;
        int dv = valid ? dw[is64 ? (base << 1) : base] : 119;
        rsum += wv;
        wn[k] = (valid && dv < NEAR_D) ? wv : 0.f;
        wm[k] = (valid && dv >= NEAR_D && dv < MID_D) ? wv : 0.f;
        wf[k] = (valid && dv >= MID_D) ? wv : 0.f;
        aw[k] = jj * STRIDE + 119 - dv;
    }
    #pragma unroll
    for (int o = 1; o < 64; o <<= 1) rsum += __shfl_xor(rsum, o, 64);

    float x = hx[2 * i], y = hx[2 * i + 1];

    #pragma unroll 1
    for (int m = 0; m < 25; ++m) {
        const int tb = 16 * m;                // synchronized macro-block [tb, tb+16)

        // ---- far windows (d>=16): one 20-word window per edge per macro-block ----
        float fps[16];
        #pragma unroll
        for (int s = 0; s < 16; ++s) fps[s] = 0.f;

        #pragma unroll
        for (int k = 0; k < KPL; ++k) {
            bool fm = (wf[k] != 0.f);
            int a = aw[k] + tb;               // word addr at s=0
            int pp = a & 3;
            int A = a - pp;                   // 16B-aligned
            float4 q0, q1, q2, q3, q4;
            if (fm) {
                const float4* f4 = reinterpret_cast<const float4*>((const float*)xh + A);
                q0 = f4[0]; q1 = f4[1]; q2 = f4[2]; q3 = f4[3]; q4 = f4[4];
            } else {
                q0 = q1 = q2 = q3 = q4 = make_float4(0.f, 0.f, 0.f, 0.f);
            }
            float win[20] = { q0.x,q0.y,q0.z,q0.w, q1.x,q1.y,q1.z,q1.w,
                              q2.x,q2.y,q2.z,q2.w, q3.x,q3.y,q3.z,q3.w,
                              q4.x,q4.y,q4.z,q4.w };
            int g = 0;
            while (true) {                    // stale-SENT -> ALD retry (proven idiom)
                int pend = 0;
                #pragma unroll
                for (int z = 0; z < 20; ++z)
                    pend |= (int)((z >= pp) & (z < pp + 16) &
                                  (__float_as_uint(win[z]) == SENT));
                if (!__any(pend)) break;
                if (++g > 1000000) break;     // safety valve
                #pragma unroll
                for (int z = 0; z < 20; ++z)
                    if ((z >= pp) && (z < pp + 16) && __float_as_uint(win[z]) == SENT)
                        win[z] = __uint_as_float(ALD(&xh[A + z]));
            }
            float wk = wf[k];
            #pragma unroll
            for (int s = 0; s < 16; ++s) {    // value = win[pp+s] via 3 cndmask
                float v01 = (pp & 1) ? win[s + 1] : win[s];
                float v23 = (pp & 1) ? win[s + 3] : win[s + 2];
                float v   = (pp & 2) ? v23 : v01;
                fps[s] += wk * v;
            }
        }

        float fm4[4] = {0.f, 0.f, 0.f, 0.f};

        #pragma unroll
        for (int s = 0; s < 16; ++s) {
            const int t = tb + s;

            // ---- mid quad (4<=d<16): refill fm4 at quad boundary (synchronized) ----
            if ((s & 3) == 0) {
                #pragma unroll
                for (int r = 0; r < 4; ++r) fm4[r] = 0.f;
                #pragma unroll
                for (int k = 0; k < KPL; ++k) {
                    bool mm = (wm[k] != 0.f);
                    int a = aw[k] + t;
                    int pp = a & 3;
                    int A = a - pp;
                    float4 q0, q1;
                    if (mm) {
                        const float4* f4 = reinterpret_cast<const float4*>((const float*)xh + A);
                        q0 = f4[0]; q1 = f4[1];
                    } else {
                        q0 = q1 = make_float4(0.f, 0.f, 0.f, 0.f);
                    }
                    float win[8] = { q0.x,q0.y,q0.z,q0.w, q1.x,q1.y,q1.z,q1.w };
                    int g = 0;
                    while (true) {
                        int pend = 0;
                        #pragma unroll
                        for (int z = 0; z < 8; ++z)
                            pend |= (int)((z >= pp) & (z < pp + 4) &
                                          (__float_as_uint(win[z]) == SENT));
                        if (!__any(pend)) break;
                        if (++g > 1000000) break;   // safety valve
                        #pragma unroll
                        for (int z = 0; z < 8; ++z)
                            if ((z >= pp) && (z < pp + 4) && __float_as_uint(win[z]) == SENT)
                                win[z] = __uint_as_float(ALD(&xh[A + z]));
                    }
                    float wk = wm[k];
                    #pragma unroll
                    for (int r = 0; r < 4; ++r) {
                        float v01 = (pp & 1) ? win[r + 1] : win[r];
                        float v23 = (pp & 1) ? win[r + 3] : win[r + 2];
                        float v   = (pp & 2) ? v23 : v01;
                        fm4[r] += wk * v;
                    }
                }
            }

            // ---- near poll (d<4): ~27 cells, proven elastic pattern ----
            unsigned int vv[KPL];
            #pragma unroll
            for (int k = 0; k < KPL; ++k)
                vv[k] = (wn[k] != 0.f) ? ALD(&xh[aw[k] + t]) : 0u;
            int g = 0;
            while (true) {
                int pend = 0;
                #pragma unroll
                for (int k = 0; k < KPL; ++k) pend |= (vv[k] == SENT) ? 1 : 0;
                if (!__any(pend)) break;
                if (++g > 1000000) break;           // safety valve
                #pragma unroll
                for (int k = 0; k < KPL; ++k)
                    if (vv[k] == SENT) vv[k] = ALD(&xh[aw[k] + t]);
            }
            float acc = fps[s] + fm4[s & 3];
            #pragma unroll
            for (int k = 0; k < KPL; ++k) acc += wn[k] * __uint_as_float(vv[k]);
            #pragma unroll
            for (int o = 1; o < 64; o <<= 1) acc += __shfl_xor(acc, o, 64);

            // ---- integrate / publish ----
            int tr = (t * 205) >> 11;               // t/10 for t<400
            int sp = t - tr * 10;
            float u  = external[(i * SPT_ + sp) * TRS_ + tr];
            float n0 = noise[(t * N_ + i) * 2 + 0];
            float n1 = noise[(t * N_ + i) * 2 + 1];

            float r2 = x * x + y * y;
            float dx = (A_F - r2) * x - OMEGA_F * y + G_F * (acc - rsum * x) + KGI_F * u;
            float dy = (A_F - r2) * y + OMEGA_F * x;
            x = x + DT_F * dx + n0;
            y = y + DT_F * dy + n1;

            if (lane == 0) {
                AST(&xh[i * STRIDE + 120 + t], __float_as_uint(x));
                if (sp == SPT_ - 1) xtr[tr * N_ + i] = x;
            }
        }
    }

    grid.sync();   // make xtr visible for the epilogue

    // epilogue: out[c*TRS + tr] = 5 * dot(xtr[tr,:], lm[c,:]) - 2
    for (int o = i; o < C_ * TRS_; o += 800) {
        int c = o / TRS_, tr = o - c * TRS_;
        float s = 0.f;
        #pragma unroll
        for (int k = 0; k < KPL; ++k) {
            int n = k * 64 + lane;
            if (n < N_) s += xtr[tr * N_ + n] * lm[c * N_ + n];
        }
        #pragma unroll
        for (int o2 = 1; o2 < 64; o2 <<= 1) s += __shfl_xor(s, o2, 64);
        if (lane == 0) out[o] = 5.0f * s - 2.0f;
    }
}

// ---------------- launch (identical shape to champion R0) ----------------

extern "C" void kernel_launch(void* const* d_in, const int* in_sizes, int n_in,
                              void* d_out, int out_size, void* d_ws, size_t ws_size,
                              hipStream_t stream) {
    const float* external = (const float*)d_in[0];
    const float* hx       = (const float*)d_in[1];
    const float* hE       = (const float*)d_in[2];
    const float* sc       = (const float*)d_in[3];
    const float* lm       = (const float*)d_in[4];
    const float* noise    = (const float*)d_in[5];
    const int*   delays   = (const int*)  d_in[6];
    float* out = (float*)d_out;

    float*        sumsq = (float*)d_ws;                    // ws[0]
    int*          flag  = (int*)d_ws + 1;                  // ws[1]
    unsigned int* xh    = (unsigned int*)d_ws + 64;        // 800*528 words
    float*        xtr   = (float*)(xh + N_ * STRIDE);      // 40*800 floats

    hipMemsetAsync(d_ws, 0, 8, stream);
    k_sumsq<<<256, 256, 0, stream>>>(sc, sumsq);
    k_detect<<<1, 256, 0, stream>>>(delays, flag);
    k_init<<<(N_ * 520 + 255) / 256, 256, 0, stream>>>(hE, xh);

    void* args[] = { (void*)&sc, (void*)&delays, (void*)&hx, (void*)&external,
                     (void*)&noise, (void*)&lm, (void*)&sumsq, (void*)&flag,
                     (void*)&xh, (void*)&xtr, (void*)&out };
    hipLaunchCooperativeKernel((const void*)k_main, dim3(100), dim3(512), args, 0, stream);
}

// Round 8
// 4003.603 us; speedup vs baseline: 1.8443x; 1.3862x over previous
//
#include <hip/hip_runtime.h>
#include <hip/hip_cooperative_groups.h>

namespace cg = cooperative_groups;

#define N_      800
#define C_      64
#define TRS_    40
#define SPT_    10
#define BUF_    120
#define T_      400
#define STRIDE  528           // per-row history stride in words (520 used)
#define KPL     13            // edges per lane: 13*64 = 832 >= 800
#define SENT    0x7FC00BADu   // qNaN sentinel for "not yet written"
#define NEAR_D  15            // d < 15 -> per-step masked ALD poll; d >= 15 -> far windows

#define A_F     (-0.5f)
#define OMEGA_F (10.0f)
#define G_F     (500.0f)
#define KGI_F   (5.0f)
#define DT_F    (1e-4f)

#define ALD(p)    __hip_atomic_load((p), __ATOMIC_RELAXED, __HIP_MEMORY_SCOPE_AGENT)
#define AST(p,v)  __hip_atomic_store((p), (v), __ATOMIC_RELAXED, __HIP_MEMORY_SCOPE_AGENT)

typedef unsigned int u32x4 __attribute__((ext_vector_type(4)));

// ---------------- prelude kernels (unchanged, proven) ----------------

__global__ void k_sumsq(const float* __restrict__ sc, float* __restrict__ sumsq) {
    __shared__ float sh[4];
    int tid = threadIdx.x;
    int idx = blockIdx.x * 256 + tid;
    float s = 0.f;
    for (int i = idx; i < N_ * N_; i += 256 * 256) { float v = sc[i]; s += v * v; }
    #pragma unroll
    for (int o = 1; o < 64; o <<= 1) s += __shfl_xor(s, o, 64);
    if ((tid & 63) == 0) sh[tid >> 6] = s;
    __syncthreads();
    if (tid == 0) atomicAdd(sumsq, sh[0] + sh[1] + sh[2] + sh[3]);
}

__global__ void k_detect(const int* __restrict__ dw, int* __restrict__ flag) {
    __shared__ int sh[4];
    int tid = threadIdx.x;
    int v = 0;
    for (int idx = 2 * tid + 1; idx < 800; idx += 512) v |= dw[idx];
    #pragma unroll
    for (int o = 1; o < 64; o <<= 1) v |= __shfl_xor(v, o, 64);
    if ((tid & 63) == 0) sh[tid >> 6] = v;
    __syncthreads();
    if (tid == 0) flag[0] = ((sh[0] | sh[1] | sh[2] | sh[3]) == 0) ? 1 : 0; // 1 => int64
}

// linear history: row j, time tau at slot tau+120 (tau in [-120,399])
__global__ void k_init(const float* __restrict__ hE, unsigned int* __restrict__ xh) {
    int idx = blockIdx.x * 256 + threadIdx.x;
    if (idx >= N_ * 520) return;
    int j = idx / 520, s = idx - j * 520;
    unsigned int v = (s < 120) ? __float_as_uint(hE[j * BUF_ + (119 - s)]) : SENT;
    xh[j * STRIDE + s] = v;
}

// ---------------- main persistent kernel ----------------
// EXACT champion (R0, 2729 us) with ONE change: far-window first-attempt reads
// use __builtin_nontemporal_load (no L2 allocate). Rationale: agent-scope
// stores from other XCDs never invalidate remote L2 lines, so plain reads that
// once cached a SENT-bearing line keep hitting stale-SENT forever, degrading
// the vectorized window into per-word scattered ALD retries. nt reads stop
// stale-line accumulation entirely; SENT-retry idiom kept for correctness.

__global__ void __launch_bounds__(512, 1) k_main(
    const float* __restrict__ sc, const int* __restrict__ dw,
    const float* __restrict__ hx, const float* __restrict__ external,
    const float* __restrict__ noise, const float* __restrict__ lm,
    const float* __restrict__ sumsq, const int* __restrict__ flag,
    unsigned int* __restrict__ xh, float* __restrict__ xtr, float* __restrict__ out)
{
    cg::grid_group grid = cg::this_grid();
    const int lane = threadIdx.x & 63;
    const int i = (int)((blockIdx.x * 512 + threadIdx.x) >> 6); // row 0..799

    const float inv_norm = 1.0f / sqrtf(*sumsq);
    const int is64 = *flag;

    // ---- per-lane edge metadata ----
    float wn[KPL], wf[KPL]; int an[KPL], af[KPL];
    float rsum = 0.f;
    #pragma unroll
    for (int k = 0; k < KPL; ++k) {
        int j = k * 64 + lane;
        bool valid = (j < N_);
        int jj = valid ? j : 0;
        int base = i * N_ + jj;
        float wv = valid ? fabsf(sc[base]) * inv_norm : 0.f;
        int dv = valid ? dw[is64 ? (base << 1) : base] : 119;
        rsum += wv;
        bool nearc = valid && (dv < NEAR_D);
        bool farc  = valid && (dv >= NEAR_D);
        wn[k] = nearc ? wv : 0.f;
        wf[k] = farc  ? wv : 0.f;
        an[k] = jj * STRIDE + 119 - (nearc ? dv : 119);
        af[k] = jj * STRIDE + 119 - (farc  ? dv : 119);
    }
    #pragma unroll
    for (int o = 1; o < 64; o <<= 1) rsum += __shfl_xor(rsum, o, 64);

    float x = hx[2 * i], y = hx[2 * i + 1];   // uniform across the wave

    #pragma unroll 1
    for (int mb = 0; mb < 25; ++mb) {
        const int t0 = mb * 16;

        // ---- far prologue: one window at a time, accumulate into fps[16] ----
        float fps[16];
        #pragma unroll
        for (int s = 0; s < 16; ++s) fps[s] = 0.f;

        #pragma unroll
        for (int k = 0; k < KPL; ++k) {
            bool fm = (wf[k] != 0.f);
            int a = af[k] + t0;            // word addr needed at s=0
            int p = a & 3;                 // constant per edge (t0 % 4 == 0)
            int A = a - p;                 // 16B-aligned
            u32x4 q0, q1, q2, q3, q4;
            if (fm) {
                const u32x4* f4 = reinterpret_cast<const u32x4*>((const float*)xh + A);
                q0 = __builtin_nontemporal_load(f4 + 0);   // nt: no L2 allocate
                q1 = __builtin_nontemporal_load(f4 + 1);
                q2 = __builtin_nontemporal_load(f4 + 2);
                q3 = __builtin_nontemporal_load(f4 + 3);
                q4 = __builtin_nontemporal_load(f4 + 4);
            } else {
                q0 = q1 = q2 = q3 = q4 = (u32x4)(0u);
            }
            float win[20] = {
                __uint_as_float(q0.x), __uint_as_float(q0.y), __uint_as_float(q0.z), __uint_as_float(q0.w),
                __uint_as_float(q1.x), __uint_as_float(q1.y), __uint_as_float(q1.z), __uint_as_float(q1.w),
                __uint_as_float(q2.x), __uint_as_float(q2.y), __uint_as_float(q2.z), __uint_as_float(q2.w),
                __uint_as_float(q3.x), __uint_as_float(q3.y), __uint_as_float(q3.z), __uint_as_float(q3.w),
                __uint_as_float(q4.x), __uint_as_float(q4.y), __uint_as_float(q4.z), __uint_as_float(q4.w) };
            // cells are monotonic SENT->value; any SENT -> ALD retry
            int g = 0;
            while (true) {
                int pend = 0;
                #pragma unroll
                for (int z = 0; z < 20; ++z)
                    pend |= (int)((z >= p) & (z < p + 16) &
                                  (__float_as_uint(win[z]) == SENT));
                if (!__any(pend)) break;
                if (++g > 1000000) break;   // safety valve (never expected)
                #pragma unroll
                for (int z = 0; z < 20; ++z)
                    if ((z >= p) && (z < p + 16) && __float_as_uint(win[z]) == SENT)
                        win[z] = __uint_as_float(ALD(&xh[A + z]));
            }
            float wk = wf[k];
            #pragma unroll
            for (int s = 0; s < 16; ++s) {  // value = win[p+s] via 3 cndmask
                float v01 = (p & 1) ? win[s + 1] : win[s];
                float v23 = (p & 1) ? win[s + 3] : win[s + 2];
                float v   = (p & 2) ? v23 : v01;
                fps[s] += wk * v;
            }
        }

        // ---- 16 integration steps ----
        #pragma unroll
        for (int s = 0; s < 16; ++s) {
            const int t = t0 + s;
            int tr = (t * 205) >> 11;       // t/10 for t<400
            int sp = t - tr * 10;
            float u  = external[(i * SPT_ + sp) * TRS_ + tr];
            float n0 = noise[(t * N_ + i) * 2 + 0];
            float n1 = noise[(t * N_ + i) * 2 + 1];

            // near gather: exec-masked scattered ALD loads, poll until non-sentinel
            unsigned vv[KPL];
            #pragma unroll
            for (int k = 0; k < KPL; ++k)
                vv[k] = (wn[k] != 0.f) ? ALD(&xh[an[k] + t]) : 0u;
            int g = 0;
            while (true) {
                int pend = 0;
                #pragma unroll
                for (int k = 0; k < KPL; ++k) pend |= (vv[k] == SENT) ? 1 : 0;
                if (!__any(pend)) break;
                if (++g > 1000000) break;   // safety valve
                #pragma unroll
                for (int k = 0; k < KPL; ++k)
                    if (vv[k] == SENT) vv[k] = ALD(&xh[an[k] + t]);
            }
            float acc = fps[s];
            #pragma unroll
            for (int k = 0; k < KPL; ++k) acc += wn[k] * __uint_as_float(vv[k]);
            #pragma unroll
            for (int o = 1; o < 64; o <<= 1) acc += __shfl_xor(acc, o, 64);

            float r2 = x * x + y * y;
            float dx = (A_F - r2) * x - OMEGA_F * y + G_F * (acc - rsum * x) + KGI_F * u;
            float dy = (A_F - r2) * y + OMEGA_F * x;
            x = x + DT_F * dx + n0;
            y = y + DT_F * dy + n1;

            if (lane == 0) {
                AST(&xh[i * STRIDE + 120 + t], __float_as_uint(x));
                if (sp == SPT_ - 1) xtr[tr * N_ + i] = x;
            }
        }
    }

    grid.sync();   // single barrier: make xtr visible for the epilogue

    // epilogue: out[c*TRS + tr] = 5 * dot(xtr[tr,:], lm[c,:]) - 2
    for (int o = i; o < C_ * TRS_; o += 800) {
        int c = o / TRS_, tr = o - c * TRS_;
        float s = 0.f;
        #pragma unroll
        for (int k = 0; k < KPL; ++k) {
            int n = k * 64 + lane;
            if (n < N_) s += xtr[tr * N_ + n] * lm[c * N_ + n];
        }
        #pragma unroll
        for (int o2 = 1; o2 < 64; o2 <<= 1) s += __shfl_xor(s, o2, 64);
        if (lane == 0) out[o] = 5.0f * s - 2.0f;
    }
}

// ---------------- launch (identical shape to proven champion) ----------------

extern "C" void kernel_launch(void* const* d_in, const int* in_sizes, int n_in,
                              void* d_out, int out_size, void* d_ws, size_t ws_size,
                              hipStream_t stream) {
    const float* external = (const float*)d_in[0];
    const float* hx       = (const float*)d_in[1];
    const float* hE       = (const float*)d_in[2];
    const float* sc       = (const float*)d_in[3];
    const float* lm       = (const float*)d_in[4];
    const float* noise    = (const float*)d_in[5];
    const int*   delays   = (const int*)  d_in[6];
    float* out = (float*)d_out;

    float*        sumsq = (float*)d_ws;                    // ws[0]
    int*          flag  = (int*)d_ws + 1;                  // ws[1]
    unsigned int* xh    = (unsigned int*)d_ws + 64;        // 800*528 words
    float*        xtr   = (float*)(xh + N_ * STRIDE);      // 40*800 floats

    hipMemsetAsync(d_ws, 0, 8, stream);
    k_sumsq<<<256, 256, 0, stream>>>(sc, sumsq);
    k_detect<<<1, 256, 0, stream>>>(delays, flag);
    k_init<<<(N_ * 520 + 255) / 256, 256, 0, stream>>>(hE, xh);

    void* args[] = { (void*)&sc, (void*)&delays, (void*)&hx, (void*)&external,
                     (void*)&noise, (void*)&lm, (void*)&sumsq, (void*)&flag,
                     (void*)&xh, (void*)&xtr, (void*)&out };
    hipLaunchCooperativeKernel((const void*)k_main, dim3(100), dim3(512), args, 0, stream);
}